// Round 1
// baseline (3417.173 us; speedup 1.0000x reference)
//
#include <hip/hip_runtime.h>
#include <hip/hip_bf16.h>
#include <stdint.h>

typedef __bf16 bf16x8 __attribute__((ext_vector_type(8)));
typedef float f32x4 __attribute__((ext_vector_type(4)));

#define Bb 64
#define Ss 2048
#define Ff 1024
#define Hh 1024
#define Ll 128
#define NCc 16

// fp32 -> bf16 round-to-nearest-even (bias-free; truncation would accumulate)
__device__ __forceinline__ uint16_t f2bf_rne(float x) {
    union { float f; uint32_t u; } c; c.f = x;
    uint32_t u = c.u;
    return (uint16_t)((u + 0x7FFFu + ((u >> 16) & 1u)) >> 16);
}

__device__ __forceinline__ void load_lds16(const void* g, void* l) {
    __builtin_amdgcn_global_load_lds(
        (__attribute__((address_space(1))) void*)(uintptr_t)g,
        (__attribute__((address_space(3))) void*)l, 16, 0, 0);
}

// ---------------- prep: bf16 weights, bias sum, zero h0 ----------------
__global__ __launch_bounds__(256) void prep_kernel(
    const float* __restrict__ Wih, const float* __restrict__ Whh,
    const float* __restrict__ bih, const float* __restrict__ bhh,
    uint16_t* __restrict__ wih_bf, uint16_t* __restrict__ whh_bf,
    uint16_t* __restrict__ h0, float* __restrict__ bias)
{
    int i = blockIdx.x * 256 + threadIdx.x;   // grid 4096*256 = 1048576 exactly
    wih_bf[i] = f2bf_rne(Wih[i]);
    whh_bf[i] = f2bf_rne(Whh[i]);
    h0[i] = 0;
    if (i < Hh) bias[i] = bih[i] + bhh[i];
}

// ---------------- xproj GEMM: out[map(t,n), h] = sum_f x[row(t,n), f]*Wih[h,f] + bias[h]
// grid (8, 1024): x = h-block (fastest, shares A tile in L2), y = m-block. 256 thr.
__global__ __launch_bounds__(256) void xproj_kernel(
    const float* __restrict__ x, const uint16_t* __restrict__ wih,
    const float* __restrict__ bias, float* __restrict__ out)
{
    __shared__ __bf16 As[128*32];
    __shared__ __bf16 Bs[128*32];
    const int hb = blockIdx.x, mb = blockIdx.y;
    const int tid = threadIdx.x;
    const int wave = tid >> 6, lane = tid & 63;
    const int wm = (wave >> 1) * 64, wn = (wave & 1) * 64;

    const int t  = mb >> 3;            // reversed-time index (same for whole block)
    const int n0 = (mb & 7) * 128;     // sequence-block base

    int arow[4], acol[4];
#pragma unroll
    for (int p = 0; p < 4; ++p) {
        int idx = p*256 + tid;
        int r = idx >> 3, c4 = idx & 7;
        int n = n0 + r;
        int b = n >> 4, c = n & 15;
        arow[p] = b*Ss + c*Ll + (Ll-1-t);   // reversed time within chunk
        acol[p] = c4*4;
    }

    f32x4 acc[4][4] = {};

    for (int k0 = 0; k0 < Ff; k0 += 32) {
        __syncthreads();
        // B tile (W_ih bf16, B^T form): 128 rows x 32 cols, width-16 direct-to-LDS
#pragma unroll
        for (int p = 0; p < 2; ++p) {
            int idx = p*256 + tid;
            int r = idx >> 2, c = idx & 3;
            load_lds16(wih + (size_t)(hb*128 + r)*1024 + (k0 + c*8), (char*)Bs + idx*16);
        }
        // A tile: fp32 load + RNE cvt + ds_write_b64 (lane-contiguous, conflict-free)
#pragma unroll
        for (int p = 0; p < 4; ++p) {
            int idx = p*256 + tid;
            const float4 v = *(const float4*)(x + (size_t)arow[p]*Ff + k0 + acol[p]);
            uint32_t lo = (uint32_t)f2bf_rne(v.x) | ((uint32_t)f2bf_rne(v.y) << 16);
            uint32_t hi = (uint32_t)f2bf_rne(v.z) | ((uint32_t)f2bf_rne(v.w) << 16);
            *(uint2*)((char*)As + idx*8) = make_uint2(lo, hi);
        }
        __syncthreads();

        bf16x8 af[4], bfr[4];
#pragma unroll
        for (int i = 0; i < 4; ++i)
            af[i] = *(const bf16x8*)&As[(wm + i*16 + (lane & 15))*32 + (lane >> 4)*8];
#pragma unroll
        for (int j = 0; j < 4; ++j)
            bfr[j] = *(const bf16x8*)&Bs[(wn + j*16 + (lane & 15))*32 + (lane >> 4)*8];
#pragma unroll
        for (int i = 0; i < 4; ++i)
#pragma unroll
            for (int j = 0; j < 4; ++j)
                acc[i][j] = __builtin_amdgcn_mfma_f32_16x16x32_bf16(af[i], bfr[j], acc[i][j], 0, 0, 0);
    }

    float bsv[4]; int coln[4];
#pragma unroll
    for (int j = 0; j < 4; ++j) {
        coln[j] = hb*128 + wn + j*16 + (lane & 15);
        bsv[j] = bias[coln[j]];
    }
#pragma unroll
    for (int i = 0; i < 4; ++i) {
#pragma unroll
        for (int r = 0; r < 4; ++r) {
            int n = n0 + wm + i*16 + (lane >> 4)*4 + r;
            int b = n >> 4, c = n & 15;
            size_t orow = (size_t)b*Ss + (size_t)(NCc-1-c)*Ll + (Ll-1-t);
            float* orp = out + orow*Hh;
#pragma unroll
            for (int j = 0; j < 4; ++j)
                orp[coln[j]] = acc[i][j][r] + bsv[j];
        }
    }
}

// ---------------- scan step: h_new = tanh(xp + h_prev @ Whh^T), in-place in out
// grid (16,16): x = h-block(64), y = n-block(64); 256 thr = 4 waves of 32x32
__global__ __launch_bounds__(256) void step_kernel(
    const uint16_t* __restrict__ hprev, uint16_t* __restrict__ hnext,
    const uint16_t* __restrict__ whh, float* __restrict__ out, int t)
{
    __shared__ __bf16 As[64*32];
    __shared__ __bf16 Bs[64*32];
    const int hb = blockIdx.x, nb = blockIdx.y;
    const int tid = threadIdx.x;
    const int wave = tid >> 6, lane = tid & 63;
    const int wm = (wave >> 1)*32, wn = (wave & 1)*32;

    const int sr = tid >> 2, sc = (tid & 3)*8;

    f32x4 acc[2][2] = {};

    for (int k0 = 0; k0 < Hh; k0 += 32) {
        __syncthreads();
        load_lds16(hprev + (size_t)(nb*64 + sr)*1024 + k0 + sc, (char*)As + tid*16);
        load_lds16(whh   + (size_t)(hb*64 + sr)*1024 + k0 + sc, (char*)Bs + tid*16);
        __syncthreads();

        bf16x8 af[2], bfr[2];
#pragma unroll
        for (int i = 0; i < 2; ++i)
            af[i] = *(const bf16x8*)&As[(wm + i*16 + (lane & 15))*32 + (lane >> 4)*8];
#pragma unroll
        for (int j = 0; j < 2; ++j)
            bfr[j] = *(const bf16x8*)&Bs[(wn + j*16 + (lane & 15))*32 + (lane >> 4)*8];
#pragma unroll
        for (int i = 0; i < 2; ++i)
#pragma unroll
            for (int j = 0; j < 2; ++j)
                acc[i][j] = __builtin_amdgcn_mfma_f32_16x16x32_bf16(af[i], bfr[j], acc[i][j], 0, 0, 0);
    }

#pragma unroll
    for (int i = 0; i < 2; ++i) {
#pragma unroll
        for (int r = 0; r < 4; ++r) {
            int n = nb*64 + wm + (lane >> 4)*4 + i*16 + r;
            int b = n >> 4, c = n & 15;
            size_t orow = (size_t)b*Ss + (size_t)(NCc-1-c)*Ll + (Ll-1-t);
            float* orp = out + orow*Hh;
            uint16_t* hnp = hnext + (size_t)n*Hh;
#pragma unroll
            for (int j = 0; j < 2; ++j) {
                int col = hb*64 + wn + j*16 + (lane & 15);
                float z = orp[col] + acc[i][j][r];
                float e = __expf(2.0f*z);          // tanh via exp, exact formula
                float h = 1.0f - 2.0f/(e + 1.0f);
                orp[col] = h;
                hnp[col] = f2bf_rne(h);
            }
        }
    }
}

// ---------------- final hidden state: h_final[b,:] = ys[b, 0, :] ----------------
__global__ __launch_bounds__(256) void final_kernel(float* __restrict__ out) {
    int i = blockIdx.x*256 + threadIdx.x;   // 65536
    int b = i >> 10, h = i & 1023;
    out[(size_t)Bb*Ss*Hh + i] = out[(size_t)b*Ss*Hh + h];
}

extern "C" void kernel_launch(void* const* d_in, const int* in_sizes, int n_in,
                              void* d_out, int out_size, void* d_ws, size_t ws_size,
                              hipStream_t stream)
{
    const float* x   = (const float*)d_in[0];
    // d_in[1] = hidden_state (zeros, unused: every chunk starts from 0)
    const float* Wih = (const float*)d_in[2];
    const float* Whh = (const float*)d_in[3];
    const float* bih = (const float*)d_in[4];
    const float* bhh = (const float*)d_in[5];
    float* out = (float*)d_out;

    char* ws = (char*)d_ws;
    uint16_t* wih_bf = (uint16_t*)(ws);
    uint16_t* whh_bf = (uint16_t*)(ws + (size_t)(2<<20));
    uint16_t* hb0    = (uint16_t*)(ws + (size_t)(4<<20));
    uint16_t* hb1    = (uint16_t*)(ws + (size_t)(6<<20));
    float*    bias   = (float*)(ws + (size_t)(8<<20));

    prep_kernel<<<4096, 256, 0, stream>>>(Wih, Whh, bih, bhh, wih_bf, whh_bf, hb0, bias);
    xproj_kernel<<<dim3(8, 1024), 256, 0, stream>>>(x, wih_bf, bias, out);
    for (int t = 0; t < 128; ++t) {
        const uint16_t* hp = (t & 1) ? hb1 : hb0;
        uint16_t*       hn = (t & 1) ? hb0 : hb1;
        step_kernel<<<dim3(16, 16), 256, 0, stream>>>(hp, hn, whh_bf, out, t);
    }
    final_kernel<<<256, 256, 0, stream>>>(out);
}